// Round 2
// baseline (1690.980 us; speedup 1.0000x reference)
//
#include <hip/hip_runtime.h>
#include <stdint.h>
#include <stddef.h>

// SwinBlock (shifted window attention + adaLN + MLP), MI355X gfx950.
// Round 9: GEMM staging reg->global_load_lds (width=16). The proj GEMM was
// 89.6us at MfmaUtil 17% / VALUBusy 40% — staging-bound (m151: reg-staged
// 128-tile = 646 TF vs global_load_lds = 874 TF). LDS write order was
// already linear in (wave,lane) so the swap is exact. 2-barrier schedule
// and LDS layout unchanged (T2 swizzle is null at 2-phase per regime gate).
// B=8, H=W=64, C=768, HEADS=16, CH=48, WIN=8x8 shifted (4,4), tokens=32768.

typedef __bf16 bf16;
typedef __bf16 bf16x8 __attribute__((ext_vector_type(8)));
typedef float  f32x4  __attribute__((ext_vector_type(4)));

#define GLDS16(gp, lp)                                              \
  __builtin_amdgcn_global_load_lds(                                 \
      (const __attribute__((address_space(1))) void*)(gp),          \
      (__attribute__((address_space(3))) void*)(lp), 16, 0, 0)

// ---------------------------------------------------------------------------
// Weight transpose + downconvert: in (K,N) fp32 -> out (N,K) bf16.
// ---------------------------------------------------------------------------
__global__ __launch_bounds__(256) void transpose_f32(
    const float* __restrict__ in, bf16* __restrict__ out, int K, int N) {
  __shared__ bf16 tile[32][33];
  const int k0 = blockIdx.x * 32, n0 = blockIdx.y * 32;
  const int tx = threadIdx.x & 31, ty = threadIdx.x >> 5;
#pragma unroll
  for (int j = 0; j < 32; j += 8)
    tile[ty + j][tx] = (bf16)in[(size_t)(k0 + ty + j) * N + n0 + tx];
  __syncthreads();
#pragma unroll
  for (int j = 0; j < 32; j += 8)
    out[(size_t)(n0 + ty + j) * K + k0 + tx] = tile[tx][ty + j];
}

// ---------------------------------------------------------------------------
// adaLN MLP: h = silu(mod @ w1 + b1)  (8 x 768), fp32.
// grid (8, 24): 32 outputs/block, 8 K-groups of 96.
// ---------------------------------------------------------------------------
__global__ __launch_bounds__(256) void ada1_kernel(
    const float* __restrict__ mod, const float* __restrict__ w1,
    const float* __restrict__ b1, float* __restrict__ h) {
  const int b = blockIdx.x, o0 = blockIdx.y * 32, t = threadIdx.x;
  const int o = t & 31, kg = t >> 5;  // 8 K-groups of 96
  __shared__ float sm[768];
  for (int j = t; j < 768; j += 256) sm[j] = mod[b * 768 + j];
  __syncthreads();
  float acc = 0.f;
  const int kb = kg * 96;
#pragma unroll 4
  for (int k = 0; k < 96; ++k)
    acc += sm[kb + k] * w1[(size_t)(kb + k) * 768 + o0 + o];
  __shared__ float red[8][32];
  red[kg][o] = acc;
  __syncthreads();
  if (t < 32) {
    float v = red[0][o] + red[1][o] + red[2][o] + red[3][o] + red[4][o] +
              red[5][o] + red[6][o] + red[7][o] + b1[o0 + o];
    h[b * 768 + o0 + o] = v / (1.f + __expf(-v));
  }
}

// m = h @ w2 + b2  (8 x 4608), fp32. grid (8, 72): 64 outputs/block,
// 4 K-groups of 192.
__global__ __launch_bounds__(256) void ada2_kernel(
    const float* __restrict__ h, const float* __restrict__ w2,
    const float* __restrict__ b2, float* __restrict__ m) {
  const int b = blockIdx.x, o0 = blockIdx.y * 64, t = threadIdx.x;
  const int o = t & 63, kg = t >> 6;  // 4 K-groups of 192
  __shared__ float sh[768];
  for (int j = t; j < 768; j += 256) sh[j] = h[b * 768 + j];
  __syncthreads();
  float acc = 0.f;
  const int kb = kg * 192;
  const float* wp = w2 + (size_t)kb * 4608 + o0 + o;
#pragma unroll 4
  for (int k = 0; k < 192; ++k) acc += sh[kb + k] * wp[(size_t)k * 4608];
  __shared__ float red[4][64];
  red[kg][o] = acc;
  __syncthreads();
  if (t < 64) {
    m[b * 4608 + o0 + o] =
        red[0][o] + red[1][o] + red[2][o] + red[3][o] + b2[o0 + o];
  }
}

// ---------------------------------------------------------------------------
// LayerNorm (ddof=1) + (a+1)*. + b modulation. SRCF32: src fp32 vs bf16.
// shifted=1: out token = window layout gathered from rolled src.
// ---------------------------------------------------------------------------
template <int SRCF32>
__global__ __launch_bounds__(256) void ln_mod_kernel(
    const void* __restrict__ src, const float* __restrict__ mvec,
    bf16* __restrict__ dst, int shifted) {
  const int t = threadIdx.x;
  const int outTok = blockIdx.x;
  int b, srcTok, aseg, bseg;
  if (shifted) {
    const int win = outTok >> 6, l = outTok & 63;
    b = win >> 6;
    const int wl = win & 63;
    const int hr = ((wl >> 3) << 3) | (l >> 3);
    const int wr = ((wl & 7) << 3) | (l & 7);
    const int hh = (hr + 60) & 63, ww = (wr + 60) & 63;  // inverse roll(+4,+4)
    srcTok = (b << 12) | (hh << 6) | ww;
    aseg = 0; bseg = 1;
  } else {
    srcTok = outTok; b = outTok >> 12; aseg = 3; bseg = 4;
  }
  float v[3];
#pragma unroll
  for (int j = 0; j < 3; ++j) {
    const size_t idx = (size_t)srcTok * 768 + t + j * 256;
    v[j] = SRCF32 ? ((const float*)src)[idx] : (float)((const bf16*)src)[idx];
  }
  float s = v[0] + v[1] + v[2];
  float q = v[0] * v[0] + v[1] * v[1] + v[2] * v[2];
#pragma unroll
  for (int o = 1; o < 64; o <<= 1) {
    s += __shfl_xor(s, o, 64);
    q += __shfl_xor(q, o, 64);
  }
  __shared__ float rS[4], rQ[4];
  const int wave = t >> 6, lane = t & 63;
  if (lane == 0) { rS[wave] = s; rQ[wave] = q; }
  __syncthreads();
  const float S = rS[0] + rS[1] + rS[2] + rS[3];
  const float Q = rQ[0] + rQ[1] + rQ[2] + rQ[3];
  const float mean = S * (1.f / 768.f);
  const float var = (Q - S * mean) * (1.f / 767.f);  // ddof=1
  const float rs = rsqrtf(var + 1e-5f);
  const float* mb = mvec + b * 4608;
#pragma unroll
  for (int j = 0; j < 3; ++j) {
    const int c = t + j * 256;
    const float a = mb[aseg * 768 + c], bb = mb[bseg * 768 + c];
    dst[(size_t)outTok * 768 + c] = (bf16)((a + 1.f) * ((v[j] - mean) * rs) + bb);
  }
}

// ---------------------------------------------------------------------------
// GEMM: A(M,K)bf16 @ Bt(N,K)^T bf16 + bias(f32). 128x128 tile, 256 thr,
// BK=32, global_load_lds staging (width=16), mfma 16x16x32 bf16, fp32 accum.
// MODE 0: +bias -> bf16           MODE 1: silu(+bias) -> bf16
// MODE 2: un-window+un-roll, y1=(x+c1*v)*rsqrt(1+c1^2) -> bf16 (scattered)
// MODE 3: out=(x+c2*v)*rsqrt(1+c2^2) -> FP32 d_out (spatial rows, +mOff)
// ---------------------------------------------------------------------------
template <int MODE>
__global__ __launch_bounds__(256) void gemm_bt(
    const bf16* __restrict__ A, const bf16* __restrict__ Bt,
    const float* __restrict__ bias, void* __restrict__ outv, int N, int K,
    int mOff, const float* __restrict__ xres, const float* __restrict__ mvec) {
  __shared__ __align__(16) bf16 sA[128 * 32];
  __shared__ __align__(16) bf16 sB[128 * 32];
  const int t = threadIdx.x;
  const int wave = t >> 6, lane = t & 63;
  const int quad = lane >> 4, l16 = lane & 15;
  const int m0 = blockIdx.x * 128, n0 = blockIdx.y * 128;
  const int wm = (wave & 1) * 64, wn = (wave >> 1) * 64;

  // Global src per lane: row m0+(t>>2), k-offset (t&3)*8. LDS dest byte
  // offset t*16 = wave*1024 + lane*16 — exactly global_load_lds's linear
  // write order (wave-uniform base + lane*16).
  const bf16* gA0 = A + (size_t)(m0 + (t >> 2)) * K + (t & 3) * 8;
  const bf16* gA1 = gA0 + (size_t)64 * K;
  const bf16* gB0 = Bt + (size_t)(n0 + (t >> 2)) * K + (t & 3) * 8;
  const bf16* gB1 = gB0 + (size_t)64 * K;
  bf16* ldsA0 = sA + wave * 512;   // bytes: wave*1024
  bf16* ldsA1 = ldsA0 + 2048;      // +4096 bytes (rows 64..127)
  bf16* ldsB0 = sB + wave * 512;
  bf16* ldsB1 = ldsB0 + 2048;

  f32x4 acc[4][4];
#pragma unroll
  for (int i = 0; i < 4; ++i)
#pragma unroll
    for (int j = 0; j < 4; ++j) acc[i][j] = (f32x4){0.f, 0.f, 0.f, 0.f};

  for (int k0 = 0; k0 < K; k0 += 32) {
    __syncthreads();  // previous iter's ds_reads complete before overwrite
    GLDS16(gA0, ldsA0);
    GLDS16(gA1, ldsA1);
    GLDS16(gB0, ldsB0);
    GLDS16(gB1, ldsB1);
    gA0 += 32; gA1 += 32; gB0 += 32; gB1 += 32;
    __syncthreads();  // compiler drains vmcnt(0) before barrier
    bf16x8 aF[4], bF[4];
#pragma unroll
    for (int i = 0; i < 4; ++i)
      aF[i] = *(const bf16x8*)&sA[(wm + i * 16 + l16) * 32 + quad * 8];
#pragma unroll
    for (int i = 0; i < 4; ++i)
      bF[i] = *(const bf16x8*)&sB[(wn + i * 16 + l16) * 32 + quad * 8];
#pragma unroll
    for (int mt = 0; mt < 4; ++mt)
#pragma unroll
      for (int nt = 0; nt < 4; ++nt)
        acc[mt][nt] = __builtin_amdgcn_mfma_f32_16x16x32_bf16(
            aF[mt], bF[nt], acc[mt][nt], 0, 0, 0);
  }

#pragma unroll
  for (int mt = 0; mt < 4; ++mt) {
#pragma unroll
    for (int nt = 0; nt < 4; ++nt) {
      const int col = n0 + wn + nt * 16 + l16;
      const float bv = bias[col];
#pragma unroll
      for (int r = 0; r < 4; ++r) {
        const int row = m0 + wm + mt * 16 + quad * 4 + r;  // chunk-local
        const float v = acc[mt][nt][r] + bv;
        if (MODE == 0) {
          ((bf16*)outv)[(size_t)row * N + col] = (bf16)v;
        } else if (MODE == 1) {
          ((bf16*)outv)[(size_t)row * N + col] = (bf16)(v / (1.f + __expf(-v)));
        } else if (MODE == 2) {
          const int grow = row + mOff;  // window token: win*64 + l
          const int win = grow >> 6, l = grow & 63;
          const int b = win >> 6, wl = win & 63;
          const int hr = ((wl >> 3) << 3) | (l >> 3);
          const int wr = ((wl & 7) << 3) | (l & 7);
          const int hh = (hr + 60) & 63, ww = (wr + 60) & 63;
          const size_t sp = ((size_t)(b << 12)) | (hh << 6) | ww;
          const float c1 = mvec[b * 4608 + 1536 + col];
          const float xv = xres[sp * 768 + col];
          ((bf16*)outv)[sp * 768 + col] =
              (bf16)((xv + c1 * v) * rsqrtf(1.f + c1 * c1));
        } else {  // MODE 3: fp32 final output
          const int grow = row + mOff;
          const int b = grow >> 12;
          const float c2 = mvec[b * 4608 + 3840 + col];
          const float xv = xres[(size_t)grow * 768 + col];
          ((float*)outv)[(size_t)grow * 768 + col] =
              (xv + c2 * v) * rsqrtf(1.f + c2 * c2);
        }
      }
    }
  }
}

// ---------------------------------------------------------------------------
// Windowed attention, one block per (local window, head). 256 thr = 4 waves.
// qkv chunk-local bf16 (64 windows x 64 tokens x 2304 [q|k|v]).
// ---------------------------------------------------------------------------
__global__ __launch_bounds__(256) void attn_win(
    const bf16* __restrict__ qkv, const float* __restrict__ theta,
    bf16* __restrict__ ao, int winBase) {
  __shared__ __align__(16) bf16 sQ[64 * 64];
  __shared__ __align__(16) bf16 sK[64 * 64];
  __shared__ __align__(16) bf16 sVT[48 * 64];
  __shared__ __align__(16) bf16 sP[64 * 64];
  const int t = threadIdx.x;
  const int winL = blockIdx.x >> 4, head = blockIdx.x & 15;
  const bf16* qrow = qkv + (size_t)winL * 64 * 2304;

  // ---- stage Q, K with rope (24 complex pairs per token) ----
  for (int i = t; i < 3072; i += 256) {
    const int mat = i / 1536;  // 0=q, 1=k
    const int p = i - mat * 1536;
    const int l = p / 24, d = p - (p / 24) * 24;
    const float ih = (float)(l >> 3), iw = (float)(l & 7);
    const float th = ih * theta[head * 24 + d] + iw * theta[384 + head * 24 + d];
    const float sn = __sinf(th), cs = __cosf(th);
    const size_t base = (size_t)l * 2304 + mat * 768 + head * 48 + 2 * d;
    const float qr = (float)qrow[base];
    const float qi = (float)qrow[base + 1];
    bf16* dst = mat ? sK : sQ;
    dst[l * 64 + 2 * d]     = (bf16)(qr * cs - qi * sn);
    dst[l * 64 + 2 * d + 1] = (bf16)(qr * sn + qi * cs);
  }
  // ---- zero-pad cols 48..63 of Q,K ----
  for (int i = t; i < 2048; i += 256) {
    const int mat = i >> 10, r = i & 1023;
    (mat ? sK : sQ)[(r >> 4) * 64 + 48 + (r & 15)] = (bf16)0.f;
  }
  // ---- stage V transposed: sVT[ch][key] ----
  for (int i = t; i < 3072; i += 256) {
    const int l = i / 48, c = i - (i / 48) * 48;
    sVT[c * 64 + l] = qrow[(size_t)l * 2304 + 1536 + head * 48 + c];
  }
  __syncthreads();

  const int wave = t >> 6, lane = t & 63;
  const int quad = lane >> 4, l16 = lane & 15;

  // ---- scores: wave w handles query rows w*16..w*16+15 vs 64 keys ----
  bf16x8 qf0 = *(const bf16x8*)&sQ[(wave * 16 + l16) * 64 + quad * 8];
  bf16x8 qf1 = *(const bf16x8*)&sQ[(wave * 16 + l16) * 64 + 32 + quad * 8];
  f32x4 sc[4];
#pragma unroll
  for (int nt = 0; nt < 4; ++nt) {
    sc[nt] = (f32x4){0.f, 0.f, 0.f, 0.f};
    bf16x8 kf0 = *(const bf16x8*)&sK[(nt * 16 + l16) * 64 + quad * 8];
    bf16x8 kf1 = *(const bf16x8*)&sK[(nt * 16 + l16) * 64 + 32 + quad * 8];
    sc[nt] = __builtin_amdgcn_mfma_f32_16x16x32_bf16(qf0, kf0, sc[nt], 0, 0, 0);
    sc[nt] = __builtin_amdgcn_mfma_f32_16x16x32_bf16(qf1, kf1, sc[nt], 0, 0, 0);
  }

  // ---- softmax per query row (C layout: col=l16 key, row=quad*4+r) ----
  const float scale = 0.14433756729740643f;  // 1/sqrt(48)
#pragma unroll
  for (int r = 0; r < 4; ++r) {
    float pv[4], mx = -3.4e38f;
#pragma unroll
    for (int nt = 0; nt < 4; ++nt) {
      pv[nt] = sc[nt][r] * scale;
      mx = fmaxf(mx, pv[nt]);
    }
#pragma unroll
    for (int o = 1; o < 16; o <<= 1) mx = fmaxf(mx, __shfl_xor(mx, o, 64));
    float sum = 0.f;
#pragma unroll
    for (int nt = 0; nt < 4; ++nt) {
      pv[nt] = __expf(pv[nt] - mx);
      sum += pv[nt];
    }
#pragma unroll
    for (int o = 1; o < 16; o <<= 1) sum += __shfl_xor(sum, o, 64);
    const float inv = 1.f / sum;
    const int row = wave * 16 + quad * 4 + r;
#pragma unroll
    for (int nt = 0; nt < 4; ++nt)
      sP[row * 64 + nt * 16 + l16] = (bf16)(pv[nt] * inv);
  }
  __syncthreads();

  // ---- O = P @ V : (16x64)@(64x48) per wave ----
  bf16x8 pf0 = *(const bf16x8*)&sP[(wave * 16 + l16) * 64 + quad * 8];
  bf16x8 pf1 = *(const bf16x8*)&sP[(wave * 16 + l16) * 64 + 32 + quad * 8];
#pragma unroll
  for (int nt = 0; nt < 3; ++nt) {
    f32x4 oc = (f32x4){0.f, 0.f, 0.f, 0.f};
    bf16x8 vf0 = *(const bf16x8*)&sVT[(nt * 16 + l16) * 64 + quad * 8];
    bf16x8 vf1 = *(const bf16x8*)&sVT[(nt * 16 + l16) * 64 + 32 + quad * 8];
    oc = __builtin_amdgcn_mfma_f32_16x16x32_bf16(pf0, vf0, oc, 0, 0, 0);
    oc = __builtin_amdgcn_mfma_f32_16x16x32_bf16(pf1, vf1, oc, 0, 0, 0);
#pragma unroll
    for (int r = 0; r < 4; ++r) {
      const int row = wave * 16 + quad * 4 + r;
      ao[((size_t)(winBase + winL) * 64 + row) * 768 + head * 48 + nt * 16 +
         l16] = (bf16)oc[r];
    }
  }
}

// ---------------------------------------------------------------------------
extern "C" void kernel_launch(void* const* d_in, const int* in_sizes, int n_in,
                              void* d_out, int out_size, void* d_ws,
                              size_t ws_size, hipStream_t stream) {
  const float* x      = (const float*)d_in[0];
  const float* mod    = (const float*)d_in[1];
  const float* ada_w1 = (const float*)d_in[2];
  const float* ada_b1 = (const float*)d_in[3];
  const float* ada_w2 = (const float*)d_in[4];
  const float* ada_b2 = (const float*)d_in[5];
  const float* theta  = (const float*)d_in[6];
  const float* qkv_w  = (const float*)d_in[7];
  const float* qkv_b  = (const float*)d_in[8];
  const float* proj_w = (const float*)d_in[9];
  const float* proj_b = (const float*)d_in[10];
  const float* mlp_w1 = (const float*)d_in[11];
  const float* mlp_b1 = (const float*)d_in[12];
  const float* mlp_w2 = (const float*)d_in[13];
  const float* mlp_b2 = (const float*)d_in[14];
  float* outF = (float*)d_out;  // 25,165,824 fp32 = 100.66 MB
  // Upper half of d_out (bytes 50.33MB..100.66MB) = 25,165,824 bf16 slots:
  // used as AO (attention out), then as Z (LN2 out). Lifetime-safe: mlp2
  // chunk c writes fp32 bytes [c*12.58MB,(c+1)*12.58MB), which only reaches
  // Z-chunks already consumed by earlier mlp1 launches.
  bf16* UP = (bf16*)d_out + 25165824;

  char* ws = (char*)d_ws;
  size_t o = 0;
  auto alloc = [&](size_t bytes) -> char* {
    char* p = ws + o;
    o += (bytes + 255) & ~(size_t)255;
    return p;
  };
  bf16* wT_qkv  = (bf16*)alloc((size_t)2304 * 768 * 2);
  bf16* wT_proj = (bf16*)alloc((size_t)768 * 768 * 2);
  bf16* wT_m1   = (bf16*)alloc((size_t)3072 * 768 * 2);
  bf16* wT_m2   = (bf16*)alloc((size_t)768 * 3072 * 2);
  float* hada   = (float*)alloc((size_t)8 * 768 * 4);
  float* mvec   = (float*)alloc((size_t)8 * 4608 * 4);
  bf16* Y  = (bf16*)alloc((size_t)32768 * 768 * 2);   // LN1 out, then Y1
  bf16* SC = (bf16*)alloc((size_t)4096 * 3072 * 2);   // chunk scratch
  // ws total ~= 90 MB

  transpose_f32<<<dim3(24, 72), 256, 0, stream>>>(qkv_w, wT_qkv, 768, 2304);
  transpose_f32<<<dim3(24, 24), 256, 0, stream>>>(proj_w, wT_proj, 768, 768);
  transpose_f32<<<dim3(24, 96), 256, 0, stream>>>(mlp_w1, wT_m1, 768, 3072);
  transpose_f32<<<dim3(96, 24), 256, 0, stream>>>(mlp_w2, wT_m2, 3072, 768);
  ada1_kernel<<<dim3(8, 24), 256, 0, stream>>>(mod, ada_w1, ada_b1, hada);
  ada2_kernel<<<dim3(8, 72), 256, 0, stream>>>(hada, ada_w2, ada_b2, mvec);

  // LN1 + modulation, gathered into window-token layout. x fp32 -> Y bf16.
  ln_mod_kernel<1><<<32768, 256, 0, stream>>>(x, mvec, Y, 1);

  // qkv GEMM + attention, 8 chunks of 4096 rows (64 windows). AO -> UP.
  for (int c = 0; c < 8; ++c) {
    gemm_bt<0><<<dim3(32, 18), 256, 0, stream>>>(
        Y + (size_t)c * 4096 * 768, wT_qkv, qkv_b, SC, 2304, 768, 0, nullptr,
        mvec);
    attn_win<<<1024, 256, 0, stream>>>(SC, theta, UP, c * 64);
  }

  // proj GEMM; epilogue un-windows + residual (x fp32) -> Y (=Y1, bf16).
  gemm_bt<2><<<dim3(256, 6), 256, 0, stream>>>(UP, wT_proj, proj_b, Y, 768,
                                               768, 0, x, mvec);

  // LN2 + modulation (spatial layout): Y bf16 -> Z (UP).
  ln_mod_kernel<0><<<32768, 256, 0, stream>>>(Y, mvec, UP, 0);

  // MLP, 8 chunks: mlp1 (silu) -> SC, mlp2 + final residual -> d_out (fp32).
  for (int c = 0; c < 8; ++c) {
    gemm_bt<1><<<dim3(32, 24), 256, 0, stream>>>(
        UP + (size_t)c * 4096 * 768, wT_m1, mlp_b1, SC, 3072, 768, 0, nullptr,
        mvec);
    gemm_bt<3><<<dim3(32, 6), 256, 0, stream>>>(
        SC, wT_m2, mlp_b2, outF, 768, 3072, c * 4096, x, mvec);
  }
  (void)in_sizes; (void)n_in; (void)out_size; (void)ws_size;
}

// Round 3
// 1308.248 us; speedup vs baseline: 1.2926x; 1.2926x over previous
//
#include <hip/hip_runtime.h>
#include <stdint.h>
#include <stddef.h>

// SwinBlock (shifted window attention + adaLN + MLP), MI355X gfx950.
// Round 10: (a) REVERT gl_lds -> reg-staged GEMM. gl_lds pinned the load
// issue between the two barriers (LDS-write can't cross the barrier), fully
// exposing HBM latency each K-step: proj 89.6->106.8us, MfmaUtil 17->14.
// Reg-staged loads are LDS-independent so the compiler pipelines them across
// the previous iteration's MFMAs. (b) Chunk restructure: 8x4096 -> 2x16384
// rows when ws_size allows (~166MB). mlp2 was 8 launches of 192 blocks
// (0.75 blocks/CU, 3/4 of chip idle); now 768 blocks. 32 launches -> 8.
// B=8, H=W=64, C=768, HEADS=16, CH=48, WIN=8x8 shifted (4,4), tokens=32768.

typedef __bf16 bf16;
typedef __bf16 bf16x8 __attribute__((ext_vector_type(8)));
typedef float  f32x4  __attribute__((ext_vector_type(4)));

// ---------------------------------------------------------------------------
// Weight transpose + downconvert: in (K,N) fp32 -> out (N,K) bf16.
// ---------------------------------------------------------------------------
__global__ __launch_bounds__(256) void transpose_f32(
    const float* __restrict__ in, bf16* __restrict__ out, int K, int N) {
  __shared__ bf16 tile[32][33];
  const int k0 = blockIdx.x * 32, n0 = blockIdx.y * 32;
  const int tx = threadIdx.x & 31, ty = threadIdx.x >> 5;
#pragma unroll
  for (int j = 0; j < 32; j += 8)
    tile[ty + j][tx] = (bf16)in[(size_t)(k0 + ty + j) * N + n0 + tx];
  __syncthreads();
#pragma unroll
  for (int j = 0; j < 32; j += 8)
    out[(size_t)(n0 + ty + j) * K + k0 + tx] = tile[tx][ty + j];
}

// ---------------------------------------------------------------------------
// adaLN MLP: h = silu(mod @ w1 + b1)  (8 x 768), fp32.
// grid (8, 24): 32 outputs/block, 8 K-groups of 96.
// ---------------------------------------------------------------------------
__global__ __launch_bounds__(256) void ada1_kernel(
    const float* __restrict__ mod, const float* __restrict__ w1,
    const float* __restrict__ b1, float* __restrict__ h) {
  const int b = blockIdx.x, o0 = blockIdx.y * 32, t = threadIdx.x;
  const int o = t & 31, kg = t >> 5;  // 8 K-groups of 96
  __shared__ float sm[768];
  for (int j = t; j < 768; j += 256) sm[j] = mod[b * 768 + j];
  __syncthreads();
  float acc = 0.f;
  const int kb = kg * 96;
#pragma unroll 4
  for (int k = 0; k < 96; ++k)
    acc += sm[kb + k] * w1[(size_t)(kb + k) * 768 + o0 + o];
  __shared__ float red[8][32];
  red[kg][o] = acc;
  __syncthreads();
  if (t < 32) {
    float v = red[0][o] + red[1][o] + red[2][o] + red[3][o] + red[4][o] +
              red[5][o] + red[6][o] + red[7][o] + b1[o0 + o];
    h[b * 768 + o0 + o] = v / (1.f + __expf(-v));
  }
}

// m = h @ w2 + b2  (8 x 4608), fp32. grid (8, 72): 64 outputs/block,
// 4 K-groups of 192.
__global__ __launch_bounds__(256) void ada2_kernel(
    const float* __restrict__ h, const float* __restrict__ w2,
    const float* __restrict__ b2, float* __restrict__ m) {
  const int b = blockIdx.x, o0 = blockIdx.y * 64, t = threadIdx.x;
  const int o = t & 63, kg = t >> 6;  // 4 K-groups of 192
  __shared__ float sh[768];
  for (int j = t; j < 768; j += 256) sh[j] = h[b * 768 + j];
  __syncthreads();
  float acc = 0.f;
  const int kb = kg * 192;
  const float* wp = w2 + (size_t)kb * 4608 + o0 + o;
#pragma unroll 4
  for (int k = 0; k < 192; ++k) acc += sh[kb + k] * wp[(size_t)k * 4608];
  __shared__ float red[4][64];
  red[kg][o] = acc;
  __syncthreads();
  if (t < 64) {
    m[b * 4608 + o0 + o] =
        red[0][o] + red[1][o] + red[2][o] + red[3][o] + b2[o0 + o];
  }
}

// ---------------------------------------------------------------------------
// LayerNorm (ddof=1) + (a+1)*. + b modulation. SRCF32: src fp32 vs bf16.
// shifted=1: out token = window layout gathered from rolled src.
// ---------------------------------------------------------------------------
template <int SRCF32>
__global__ __launch_bounds__(256) void ln_mod_kernel(
    const void* __restrict__ src, const float* __restrict__ mvec,
    bf16* __restrict__ dst, int shifted) {
  const int t = threadIdx.x;
  const int outTok = blockIdx.x;
  int b, srcTok, aseg, bseg;
  if (shifted) {
    const int win = outTok >> 6, l = outTok & 63;
    b = win >> 6;
    const int wl = win & 63;
    const int hr = ((wl >> 3) << 3) | (l >> 3);
    const int wr = ((wl & 7) << 3) | (l & 7);
    const int hh = (hr + 60) & 63, ww = (wr + 60) & 63;  // inverse roll(+4,+4)
    srcTok = (b << 12) | (hh << 6) | ww;
    aseg = 0; bseg = 1;
  } else {
    srcTok = outTok; b = outTok >> 12; aseg = 3; bseg = 4;
  }
  float v[3];
#pragma unroll
  for (int j = 0; j < 3; ++j) {
    const size_t idx = (size_t)srcTok * 768 + t + j * 256;
    v[j] = SRCF32 ? ((const float*)src)[idx] : (float)((const bf16*)src)[idx];
  }
  float s = v[0] + v[1] + v[2];
  float q = v[0] * v[0] + v[1] * v[1] + v[2] * v[2];
#pragma unroll
  for (int o = 1; o < 64; o <<= 1) {
    s += __shfl_xor(s, o, 64);
    q += __shfl_xor(q, o, 64);
  }
  __shared__ float rS[4], rQ[4];
  const int wave = t >> 6, lane = t & 63;
  if (lane == 0) { rS[wave] = s; rQ[wave] = q; }
  __syncthreads();
  const float S = rS[0] + rS[1] + rS[2] + rS[3];
  const float Q = rQ[0] + rQ[1] + rQ[2] + rQ[3];
  const float mean = S * (1.f / 768.f);
  const float var = (Q - S * mean) * (1.f / 767.f);  // ddof=1
  const float rs = rsqrtf(var + 1e-5f);
  const float* mb = mvec + b * 4608;
#pragma unroll
  for (int j = 0; j < 3; ++j) {
    const int c = t + j * 256;
    const float a = mb[aseg * 768 + c], bb = mb[bseg * 768 + c];
    dst[(size_t)outTok * 768 + c] = (bf16)((a + 1.f) * ((v[j] - mean) * rs) + bb);
  }
}

// ---------------------------------------------------------------------------
// GEMM: A(M,K)bf16 @ Bt(N,K)^T bf16 + bias(f32). 128x128 tile, 256 thr,
// BK=32, VGPR staging (compiler pipelines the reg loads across the prev
// iteration's MFMAs — measured faster than global_load_lds here, R9),
// mfma 16x16x32 bf16, fp32 accum.
// MODE 0: +bias -> bf16           MODE 1: silu(+bias) -> bf16
// MODE 2: un-window+un-roll, y1=(x+c1*v)*rsqrt(1+c1^2) -> bf16 (scattered)
// MODE 3: out=(x+c2*v)*rsqrt(1+c2^2) -> FP32 d_out (spatial rows, +mOff)
// ---------------------------------------------------------------------------
template <int MODE>
__global__ __launch_bounds__(256) void gemm_bt(
    const bf16* __restrict__ A, const bf16* __restrict__ Bt,
    const float* __restrict__ bias, void* __restrict__ outv, int N, int K,
    int mOff, const float* __restrict__ xres, const float* __restrict__ mvec) {
  __shared__ __align__(16) bf16 sA[128 * 32];
  __shared__ __align__(16) bf16 sB[128 * 32];
  const int t = threadIdx.x;
  const int wave = t >> 6, lane = t & 63;
  const int quad = lane >> 4, l16 = lane & 15;
  const int m0 = blockIdx.x * 128, n0 = blockIdx.y * 128;
  const int wm = (wave & 1) * 64, wn = (wave >> 1) * 64;

  const bf16* gA0 = A + (size_t)(m0 + (t >> 2)) * K + (t & 3) * 8;
  const bf16* gA1 = gA0 + (size_t)64 * K;
  const bf16* gB0 = Bt + (size_t)(n0 + (t >> 2)) * K + (t & 3) * 8;
  const bf16* gB1 = gB0 + (size_t)64 * K;
  bf16* wA0 = sA + t * 8;  // elem offset t*8 == row(t>>2)*32 + (t&3)*8
  bf16* wA1 = wA0 + 2048;
  bf16* wB0 = sB + t * 8;
  bf16* wB1 = wB0 + 2048;

  f32x4 acc[4][4];
#pragma unroll
  for (int i = 0; i < 4; ++i)
#pragma unroll
    for (int j = 0; j < 4; ++j) acc[i][j] = (f32x4){0.f, 0.f, 0.f, 0.f};

  for (int k0 = 0; k0 < K; k0 += 32) {
    const bf16x8 a0 = *(const bf16x8*)gA0;
    const bf16x8 a1 = *(const bf16x8*)gA1;
    const bf16x8 b0 = *(const bf16x8*)gB0;
    const bf16x8 b1 = *(const bf16x8*)gB1;
    gA0 += 32; gA1 += 32; gB0 += 32; gB1 += 32;
    __syncthreads();
    *(bf16x8*)wA0 = a0;
    *(bf16x8*)wA1 = a1;
    *(bf16x8*)wB0 = b0;
    *(bf16x8*)wB1 = b1;
    __syncthreads();
    bf16x8 aF[4], bF[4];
#pragma unroll
    for (int i = 0; i < 4; ++i)
      aF[i] = *(const bf16x8*)&sA[(wm + i * 16 + l16) * 32 + quad * 8];
#pragma unroll
    for (int i = 0; i < 4; ++i)
      bF[i] = *(const bf16x8*)&sB[(wn + i * 16 + l16) * 32 + quad * 8];
#pragma unroll
    for (int mt = 0; mt < 4; ++mt)
#pragma unroll
      for (int nt = 0; nt < 4; ++nt)
        acc[mt][nt] = __builtin_amdgcn_mfma_f32_16x16x32_bf16(
            aF[mt], bF[nt], acc[mt][nt], 0, 0, 0);
  }

#pragma unroll
  for (int mt = 0; mt < 4; ++mt) {
#pragma unroll
    for (int nt = 0; nt < 4; ++nt) {
      const int col = n0 + wn + nt * 16 + l16;
      const float bv = bias[col];
#pragma unroll
      for (int r = 0; r < 4; ++r) {
        const int row = m0 + wm + mt * 16 + quad * 4 + r;  // chunk-local
        const float v = acc[mt][nt][r] + bv;
        if (MODE == 0) {
          ((bf16*)outv)[(size_t)row * N + col] = (bf16)v;
        } else if (MODE == 1) {
          ((bf16*)outv)[(size_t)row * N + col] = (bf16)(v / (1.f + __expf(-v)));
        } else if (MODE == 2) {
          const int grow = row + mOff;  // window token: win*64 + l
          const int win = grow >> 6, l = grow & 63;
          const int b = win >> 6, wl = win & 63;
          const int hr = ((wl >> 3) << 3) | (l >> 3);
          const int wr = ((wl & 7) << 3) | (l & 7);
          const int hh = (hr + 60) & 63, ww = (wr + 60) & 63;
          const size_t sp = ((size_t)(b << 12)) | (hh << 6) | ww;
          const float c1 = mvec[b * 4608 + 1536 + col];
          const float xv = xres[sp * 768 + col];
          ((bf16*)outv)[sp * 768 + col] =
              (bf16)((xv + c1 * v) * rsqrtf(1.f + c1 * c1));
        } else {  // MODE 3: fp32 final output
          const int grow = row + mOff;
          const int b = grow >> 12;
          const float c2 = mvec[b * 4608 + 3840 + col];
          const float xv = xres[(size_t)grow * 768 + col];
          ((float*)outv)[(size_t)grow * 768 + col] =
              (xv + c2 * v) * rsqrtf(1.f + c2 * c2);
        }
      }
    }
  }
}

// ---------------------------------------------------------------------------
// Windowed attention, one block per (local window, head). 256 thr = 4 waves.
// qkv chunk-local bf16 (chunk windows x 64 tokens x 2304 [q|k|v]).
// ---------------------------------------------------------------------------
__global__ __launch_bounds__(256) void attn_win(
    const bf16* __restrict__ qkv, const float* __restrict__ theta,
    bf16* __restrict__ ao, int winBase) {
  __shared__ __align__(16) bf16 sQ[64 * 64];
  __shared__ __align__(16) bf16 sK[64 * 64];
  __shared__ __align__(16) bf16 sVT[48 * 64];
  __shared__ __align__(16) bf16 sP[64 * 64];
  const int t = threadIdx.x;
  const int winL = blockIdx.x >> 4, head = blockIdx.x & 15;
  const bf16* qrow = qkv + (size_t)winL * 64 * 2304;

  // ---- stage Q, K with rope (24 complex pairs per token) ----
  for (int i = t; i < 3072; i += 256) {
    const int mat = i / 1536;  // 0=q, 1=k
    const int p = i - mat * 1536;
    const int l = p / 24, d = p - (p / 24) * 24;
    const float ih = (float)(l >> 3), iw = (float)(l & 7);
    const float th = ih * theta[head * 24 + d] + iw * theta[384 + head * 24 + d];
    const float sn = __sinf(th), cs = __cosf(th);
    const size_t base = (size_t)l * 2304 + mat * 768 + head * 48 + 2 * d;
    const float qr = (float)qrow[base];
    const float qi = (float)qrow[base + 1];
    bf16* dst = mat ? sK : sQ;
    dst[l * 64 + 2 * d]     = (bf16)(qr * cs - qi * sn);
    dst[l * 64 + 2 * d + 1] = (bf16)(qr * sn + qi * cs);
  }
  // ---- zero-pad cols 48..63 of Q,K ----
  for (int i = t; i < 2048; i += 256) {
    const int mat = i >> 10, r = i & 1023;
    (mat ? sK : sQ)[(r >> 4) * 64 + 48 + (r & 15)] = (bf16)0.f;
  }
  // ---- stage V transposed: sVT[ch][key] ----
  for (int i = t; i < 3072; i += 256) {
    const int l = i / 48, c = i - (i / 48) * 48;
    sVT[c * 64 + l] = qrow[(size_t)l * 2304 + 1536 + head * 48 + c];
  }
  __syncthreads();

  const int wave = t >> 6, lane = t & 63;
  const int quad = lane >> 4, l16 = lane & 15;

  // ---- scores: wave w handles query rows w*16..w*16+15 vs 64 keys ----
  bf16x8 qf0 = *(const bf16x8*)&sQ[(wave * 16 + l16) * 64 + quad * 8];
  bf16x8 qf1 = *(const bf16x8*)&sQ[(wave * 16 + l16) * 64 + 32 + quad * 8];
  f32x4 sc[4];
#pragma unroll
  for (int nt = 0; nt < 4; ++nt) {
    sc[nt] = (f32x4){0.f, 0.f, 0.f, 0.f};
    bf16x8 kf0 = *(const bf16x8*)&sK[(nt * 16 + l16) * 64 + quad * 8];
    bf16x8 kf1 = *(const bf16x8*)&sK[(nt * 16 + l16) * 64 + 32 + quad * 8];
    sc[nt] = __builtin_amdgcn_mfma_f32_16x16x32_bf16(qf0, kf0, sc[nt], 0, 0, 0);
    sc[nt] = __builtin_amdgcn_mfma_f32_16x16x32_bf16(qf1, kf1, sc[nt], 0, 0, 0);
  }

  // ---- softmax per query row (C layout: col=l16 key, row=quad*4+r) ----
  const float scale = 0.14433756729740643f;  // 1/sqrt(48)
#pragma unroll
  for (int r = 0; r < 4; ++r) {
    float pv[4], mx = -3.4e38f;
#pragma unroll
    for (int nt = 0; nt < 4; ++nt) {
      pv[nt] = sc[nt][r] * scale;
      mx = fmaxf(mx, pv[nt]);
    }
#pragma unroll
    for (int o = 1; o < 16; o <<= 1) mx = fmaxf(mx, __shfl_xor(mx, o, 64));
    float sum = 0.f;
#pragma unroll
    for (int nt = 0; nt < 4; ++nt) {
      pv[nt] = __expf(pv[nt] - mx);
      sum += pv[nt];
    }
#pragma unroll
    for (int o = 1; o < 16; o <<= 1) sum += __shfl_xor(sum, o, 64);
    const float inv = 1.f / sum;
    const int row = wave * 16 + quad * 4 + r;
#pragma unroll
    for (int nt = 0; nt < 4; ++nt)
      sP[row * 64 + nt * 16 + l16] = (bf16)(pv[nt] * inv);
  }
  __syncthreads();

  // ---- O = P @ V : (16x64)@(64x48) per wave ----
  bf16x8 pf0 = *(const bf16x8*)&sP[(wave * 16 + l16) * 64 + quad * 8];
  bf16x8 pf1 = *(const bf16x8*)&sP[(wave * 16 + l16) * 64 + 32 + quad * 8];
#pragma unroll
  for (int nt = 0; nt < 3; ++nt) {
    f32x4 oc = (f32x4){0.f, 0.f, 0.f, 0.f};
    bf16x8 vf0 = *(const bf16x8*)&sVT[(nt * 16 + l16) * 64 + quad * 8];
    bf16x8 vf1 = *(const bf16x8*)&sVT[(nt * 16 + l16) * 64 + 32 + quad * 8];
    oc = __builtin_amdgcn_mfma_f32_16x16x32_bf16(pf0, vf0, oc, 0, 0, 0);
    oc = __builtin_amdgcn_mfma_f32_16x16x32_bf16(pf1, vf1, oc, 0, 0, 0);
#pragma unroll
    for (int r = 0; r < 4; ++r) {
      const int row = wave * 16 + quad * 4 + r;
      ao[((size_t)(winBase + winL) * 64 + row) * 768 + head * 48 + nt * 16 +
         l16] = (bf16)oc[r];
    }
  }
}

// ---------------------------------------------------------------------------
extern "C" void kernel_launch(void* const* d_in, const int* in_sizes, int n_in,
                              void* d_out, int out_size, void* d_ws,
                              size_t ws_size, hipStream_t stream) {
  const float* x      = (const float*)d_in[0];
  const float* mod    = (const float*)d_in[1];
  const float* ada_w1 = (const float*)d_in[2];
  const float* ada_b1 = (const float*)d_in[3];
  const float* ada_w2 = (const float*)d_in[4];
  const float* ada_b2 = (const float*)d_in[5];
  const float* theta  = (const float*)d_in[6];
  const float* qkv_w  = (const float*)d_in[7];
  const float* qkv_b  = (const float*)d_in[8];
  const float* proj_w = (const float*)d_in[9];
  const float* proj_b = (const float*)d_in[10];
  const float* mlp_w1 = (const float*)d_in[11];
  const float* mlp_b1 = (const float*)d_in[12];
  const float* mlp_w2 = (const float*)d_in[13];
  const float* mlp_b2 = (const float*)d_in[14];
  float* outF = (float*)d_out;  // 25,165,824 fp32 = 100.66 MB
  // Upper half of d_out (bytes 50.33MB..100.66MB) = 25,165,824 bf16 slots:
  // used as AO (attention out), then as Z (LN2 out). Lifetime-safe: mlp2
  // chunk c writes fp32 rows [c*CHR,(c+1)*CHR); for the last chunk that
  // region overlaps UP, but its Z-chunk was already consumed by the same
  // chunk's (earlier, stream-ordered) mlp1 launch.
  bf16* UP = (bf16*)d_out + 25165824;

  char* ws = (char*)d_ws;
  size_t o = 0;
  auto alloc = [&](size_t bytes) -> char* {
    char* p = ws + o;
    o += (bytes + 255) & ~(size_t)255;
    return p;
  };
  bf16* wT_qkv  = (bf16*)alloc((size_t)2304 * 768 * 2);
  bf16* wT_proj = (bf16*)alloc((size_t)768 * 768 * 2);
  bf16* wT_m1   = (bf16*)alloc((size_t)3072 * 768 * 2);
  bf16* wT_m2   = (bf16*)alloc((size_t)768 * 3072 * 2);
  float* hada   = (float*)alloc((size_t)8 * 768 * 4);
  float* mvec   = (float*)alloc((size_t)8 * 4608 * 4);
  bf16* Y  = (bf16*)alloc((size_t)32768 * 768 * 2);   // LN1 out, then Y1

  // Chunk size: 16384 rows if workspace allows (SC = 16384*3072*2 = 100.7MB,
  // total ~166MB), else the verified 4096-row path (SC 25MB, total ~90MB).
  const size_t scBig = (size_t)16384 * 3072 * 2;
  const size_t scSml = (size_t)4096 * 3072 * 2;
  const int big = (ws_size >= o + scBig + (4 << 20)) ? 1 : 0;
  bf16* SC = (bf16*)alloc(big ? scBig : scSml);
  const int CHR = big ? 16384 : 4096;   // rows per chunk
  const int NCH = 32768 / CHR;

  transpose_f32<<<dim3(24, 72), 256, 0, stream>>>(qkv_w, wT_qkv, 768, 2304);
  transpose_f32<<<dim3(24, 24), 256, 0, stream>>>(proj_w, wT_proj, 768, 768);
  transpose_f32<<<dim3(24, 96), 256, 0, stream>>>(mlp_w1, wT_m1, 768, 3072);
  transpose_f32<<<dim3(96, 24), 256, 0, stream>>>(mlp_w2, wT_m2, 3072, 768);
  ada1_kernel<<<dim3(8, 24), 256, 0, stream>>>(mod, ada_w1, ada_b1, hada);
  ada2_kernel<<<dim3(8, 72), 256, 0, stream>>>(hada, ada_w2, ada_b2, mvec);

  // LN1 + modulation, gathered into window-token layout. x fp32 -> Y bf16.
  ln_mod_kernel<1><<<32768, 256, 0, stream>>>(x, mvec, Y, 1);

  // qkv GEMM + attention, NCH chunks of CHR rows (CHR/64 windows). AO -> UP.
  for (int c = 0; c < NCH; ++c) {
    gemm_bt<0><<<dim3(CHR / 128, 18), 256, 0, stream>>>(
        Y + (size_t)c * CHR * 768, wT_qkv, qkv_b, SC, 2304, 768, 0, nullptr,
        mvec);
    attn_win<<<(CHR / 64) * 16, 256, 0, stream>>>(SC, theta, UP,
                                                  c * (CHR / 64));
  }

  // proj GEMM; epilogue un-windows + residual (x fp32) -> Y (=Y1, bf16).
  gemm_bt<2><<<dim3(256, 6), 256, 0, stream>>>(UP, wT_proj, proj_b, Y, 768,
                                               768, 0, x, mvec);

  // LN2 + modulation (spatial layout): Y bf16 -> Z (UP).
  ln_mod_kernel<0><<<32768, 256, 0, stream>>>(Y, mvec, UP, 0);

  // MLP, NCH chunks: mlp1 (silu) -> SC, mlp2 + final residual -> d_out fp32.
  for (int c = 0; c < NCH; ++c) {
    gemm_bt<1><<<dim3(CHR / 128, 24), 256, 0, stream>>>(
        UP + (size_t)c * CHR * 768, wT_m1, mlp_b1, SC, 3072, 768, 0, nullptr,
        mvec);
    gemm_bt<3><<<dim3(CHR / 128, 6), 256, 0, stream>>>(
        SC, wT_m2, mlp_b2, outF, 768, 3072, c * CHR, x, mvec);
  }
  (void)in_sizes; (void)n_in; (void)out_size;
}

// Round 4
// 1257.054 us; speedup vs baseline: 1.3452x; 1.0407x over previous
//
#include <hip/hip_runtime.h>
#include <stdint.h>
#include <stddef.h>

// SwinBlock (shifted window attention + adaLN + MLP), MI355X gfx950.
// Round 11: gemm_bt -> T3 "minimum 2-phase" schedule: double-buffered LDS,
// global_load_lds(16B) issued at TOP of each K-step (flies across
// ds_read+MFMA), ONE __syncthreads per step at iteration END (its implicit
// vmcnt(0) is the single drain). Fixes R9's failure (drain right after
// issue = full latency exposed). m151: gl_lds 874 vs reg-staged 646 TF.
// Also: single-chunk path (CHR=32768, SC=201MB) when ws allows -> mlp2 at
// 1536 blocks (6/CU), 5 GEMM/attn launches instead of 8+.
// B=8, H=W=64, C=768, HEADS=16, CH=48, WIN=8x8 shifted (4,4), tokens=32768.

typedef __bf16 bf16;
typedef __bf16 bf16x8 __attribute__((ext_vector_type(8)));
typedef float  f32x4  __attribute__((ext_vector_type(4)));

#define GLDS16(gp, lp)                                              \
  __builtin_amdgcn_global_load_lds(                                 \
      (const __attribute__((address_space(1))) void*)(gp),          \
      (__attribute__((address_space(3))) void*)(lp), 16, 0, 0)

// ---------------------------------------------------------------------------
// Weight transpose + downconvert: in (K,N) fp32 -> out (N,K) bf16.
// ---------------------------------------------------------------------------
__global__ __launch_bounds__(256) void transpose_f32(
    const float* __restrict__ in, bf16* __restrict__ out, int K, int N) {
  __shared__ bf16 tile[32][33];
  const int k0 = blockIdx.x * 32, n0 = blockIdx.y * 32;
  const int tx = threadIdx.x & 31, ty = threadIdx.x >> 5;
#pragma unroll
  for (int j = 0; j < 32; j += 8)
    tile[ty + j][tx] = (bf16)in[(size_t)(k0 + ty + j) * N + n0 + tx];
  __syncthreads();
#pragma unroll
  for (int j = 0; j < 32; j += 8)
    out[(size_t)(n0 + ty + j) * K + k0 + tx] = tile[tx][ty + j];
}

// ---------------------------------------------------------------------------
// adaLN MLP: h = silu(mod @ w1 + b1)  (8 x 768), fp32.
// grid (8, 24): 32 outputs/block, 8 K-groups of 96.
// ---------------------------------------------------------------------------
__global__ __launch_bounds__(256) void ada1_kernel(
    const float* __restrict__ mod, const float* __restrict__ w1,
    const float* __restrict__ b1, float* __restrict__ h) {
  const int b = blockIdx.x, o0 = blockIdx.y * 32, t = threadIdx.x;
  const int o = t & 31, kg = t >> 5;  // 8 K-groups of 96
  __shared__ float sm[768];
  for (int j = t; j < 768; j += 256) sm[j] = mod[b * 768 + j];
  __syncthreads();
  float acc = 0.f;
  const int kb = kg * 96;
#pragma unroll 4
  for (int k = 0; k < 96; ++k)
    acc += sm[kb + k] * w1[(size_t)(kb + k) * 768 + o0 + o];
  __shared__ float red[8][32];
  red[kg][o] = acc;
  __syncthreads();
  if (t < 32) {
    float v = red[0][o] + red[1][o] + red[2][o] + red[3][o] + red[4][o] +
              red[5][o] + red[6][o] + red[7][o] + b1[o0 + o];
    h[b * 768 + o0 + o] = v / (1.f + __expf(-v));
  }
}

// m = h @ w2 + b2  (8 x 4608), fp32. grid (8, 72): 64 outputs/block,
// 4 K-groups of 192.
__global__ __launch_bounds__(256) void ada2_kernel(
    const float* __restrict__ h, const float* __restrict__ w2,
    const float* __restrict__ b2, float* __restrict__ m) {
  const int b = blockIdx.x, o0 = blockIdx.y * 64, t = threadIdx.x;
  const int o = t & 63, kg = t >> 6;  // 4 K-groups of 192
  __shared__ float sh[768];
  for (int j = t; j < 768; j += 256) sh[j] = h[b * 768 + j];
  __syncthreads();
  float acc = 0.f;
  const int kb = kg * 192;
  const float* wp = w2 + (size_t)kb * 4608 + o0 + o;
#pragma unroll 4
  for (int k = 0; k < 192; ++k) acc += sh[kb + k] * wp[(size_t)k * 4608];
  __shared__ float red[4][64];
  red[kg][o] = acc;
  __syncthreads();
  if (t < 64) {
    m[b * 4608 + o0 + o] =
        red[0][o] + red[1][o] + red[2][o] + red[3][o] + b2[o0 + o];
  }
}

// ---------------------------------------------------------------------------
// LayerNorm (ddof=1) + (a+1)*. + b modulation. SRCF32: src fp32 vs bf16.
// shifted=1: out token = window layout gathered from rolled src.
// ---------------------------------------------------------------------------
template <int SRCF32>
__global__ __launch_bounds__(256) void ln_mod_kernel(
    const void* __restrict__ src, const float* __restrict__ mvec,
    bf16* __restrict__ dst, int shifted) {
  const int t = threadIdx.x;
  const int outTok = blockIdx.x;
  int b, srcTok, aseg, bseg;
  if (shifted) {
    const int win = outTok >> 6, l = outTok & 63;
    b = win >> 6;
    const int wl = win & 63;
    const int hr = ((wl >> 3) << 3) | (l >> 3);
    const int wr = ((wl & 7) << 3) | (l & 7);
    const int hh = (hr + 60) & 63, ww = (wr + 60) & 63;  // inverse roll(+4,+4)
    srcTok = (b << 12) | (hh << 6) | ww;
    aseg = 0; bseg = 1;
  } else {
    srcTok = outTok; b = outTok >> 12; aseg = 3; bseg = 4;
  }
  float v[3];
#pragma unroll
  for (int j = 0; j < 3; ++j) {
    const size_t idx = (size_t)srcTok * 768 + t + j * 256;
    v[j] = SRCF32 ? ((const float*)src)[idx] : (float)((const bf16*)src)[idx];
  }
  float s = v[0] + v[1] + v[2];
  float q = v[0] * v[0] + v[1] * v[1] + v[2] * v[2];
#pragma unroll
  for (int o = 1; o < 64; o <<= 1) {
    s += __shfl_xor(s, o, 64);
    q += __shfl_xor(q, o, 64);
  }
  __shared__ float rS[4], rQ[4];
  const int wave = t >> 6, lane = t & 63;
  if (lane == 0) { rS[wave] = s; rQ[wave] = q; }
  __syncthreads();
  const float S = rS[0] + rS[1] + rS[2] + rS[3];
  const float Q = rQ[0] + rQ[1] + rQ[2] + rQ[3];
  const float mean = S * (1.f / 768.f);
  const float var = (Q - S * mean) * (1.f / 767.f);  // ddof=1
  const float rs = rsqrtf(var + 1e-5f);
  const float* mb = mvec + b * 4608;
#pragma unroll
  for (int j = 0; j < 3; ++j) {
    const int c = t + j * 256;
    const float a = mb[aseg * 768 + c], bb = mb[bseg * 768 + c];
    dst[(size_t)outTok * 768 + c] = (bf16)((a + 1.f) * ((v[j] - mean) * rs) + bb);
  }
}

// ---------------------------------------------------------------------------
// GEMM: A(M,K)bf16 @ Bt(N,K)^T bf16 + bias(f32). 128x128 tile, 256 thr,
// BK=32, 2-phase double-buffered global_load_lds staging (T3 minimum
// recipe): stage next K-tile FIRST, then ds_read+MFMA current, then ONE
// __syncthreads (its implicit vmcnt(0) drains the in-flight stage, which
// flew across the whole compute phase). mfma 16x16x32 bf16, fp32 accum.
// MODE 0: +bias -> bf16           MODE 1: silu(+bias) -> bf16
// MODE 2: un-window+un-roll, y1=(x+c1*v)*rsqrt(1+c1^2) -> bf16 (scattered)
// MODE 3: out=(x+c2*v)*rsqrt(1+c2^2) -> FP32 d_out (spatial rows, +mOff)
// ---------------------------------------------------------------------------
template <int MODE>
__global__ __launch_bounds__(256) void gemm_bt(
    const bf16* __restrict__ A, const bf16* __restrict__ Bt,
    const float* __restrict__ bias, void* __restrict__ outv, int N, int K,
    int mOff, const float* __restrict__ xres, const float* __restrict__ mvec) {
  __shared__ __align__(16) bf16 sA[2][128 * 32];
  __shared__ __align__(16) bf16 sB[2][128 * 32];
  const int t = threadIdx.x;
  const int wave = t >> 6, lane = t & 63;
  const int quad = lane >> 4, l16 = lane & 15;
  const int m0 = blockIdx.x * 128, n0 = blockIdx.y * 128;
  const int wm = (wave & 1) * 64, wn = (wave >> 1) * 64;

  // Global src per lane: row m0+(t>>2), k-offset (t&3)*8. gl_lds writes
  // LDS at wave-uniform base + lane*16B; elem offset t*8 reproduces the
  // row(t>>2)*32 + (t&3)*8 layout the frag reads expect.
  const bf16* gA0 = A + (size_t)(m0 + (t >> 2)) * K + (t & 3) * 8;
  const bf16* gA1 = gA0 + (size_t)64 * K;
  const bf16* gB0 = Bt + (size_t)(n0 + (t >> 2)) * K + (t & 3) * 8;
  const bf16* gB1 = gB0 + (size_t)64 * K;
  const int ldsOff = wave * 512;  // elems; +lane*8 implicit in gl_lds

  f32x4 acc[4][4];
#pragma unroll
  for (int i = 0; i < 4; ++i)
#pragma unroll
    for (int j = 0; j < 4; ++j) acc[i][j] = (f32x4){0.f, 0.f, 0.f, 0.f};

  // prologue: stage K-tile 0 into buffer 0, drain.
  GLDS16(gA0, &sA[0][ldsOff]);
  GLDS16(gA1, &sA[0][ldsOff + 2048]);
  GLDS16(gB0, &sB[0][ldsOff]);
  GLDS16(gB1, &sB[0][ldsOff + 2048]);
  __syncthreads();

  int cur = 0;
  for (int k0 = 0; k0 < K; k0 += 32) {
    if (k0 + 32 < K) {  // stage NEXT tile first; flies across compute below
      const int nxt = cur ^ 1, kk = k0 + 32;
      GLDS16(gA0 + kk, &sA[nxt][ldsOff]);
      GLDS16(gA1 + kk, &sA[nxt][ldsOff + 2048]);
      GLDS16(gB0 + kk, &sB[nxt][ldsOff]);
      GLDS16(gB1 + kk, &sB[nxt][ldsOff + 2048]);
    }
    bf16x8 aF[4], bF[4];
#pragma unroll
    for (int i = 0; i < 4; ++i)
      aF[i] = *(const bf16x8*)&sA[cur][(wm + i * 16 + l16) * 32 + quad * 8];
#pragma unroll
    for (int i = 0; i < 4; ++i)
      bF[i] = *(const bf16x8*)&sB[cur][(wn + i * 16 + l16) * 32 + quad * 8];
#pragma unroll
    for (int mt = 0; mt < 4; ++mt)
#pragma unroll
      for (int nt = 0; nt < 4; ++nt)
        acc[mt][nt] = __builtin_amdgcn_mfma_f32_16x16x32_bf16(
            aF[mt], bF[nt], acc[mt][nt], 0, 0, 0);
    __syncthreads();  // single per-step drain: next-stage loads + read fence
    cur ^= 1;
  }

#pragma unroll
  for (int mt = 0; mt < 4; ++mt) {
#pragma unroll
    for (int nt = 0; nt < 4; ++nt) {
      const int col = n0 + wn + nt * 16 + l16;
      const float bv = bias[col];
#pragma unroll
      for (int r = 0; r < 4; ++r) {
        const int row = m0 + wm + mt * 16 + quad * 4 + r;  // chunk-local
        const float v = acc[mt][nt][r] + bv;
        if (MODE == 0) {
          ((bf16*)outv)[(size_t)row * N + col] = (bf16)v;
        } else if (MODE == 1) {
          ((bf16*)outv)[(size_t)row * N + col] = (bf16)(v / (1.f + __expf(-v)));
        } else if (MODE == 2) {
          const int grow = row + mOff;  // window token: win*64 + l
          const int win = grow >> 6, l = grow & 63;
          const int b = win >> 6, wl = win & 63;
          const int hr = ((wl >> 3) << 3) | (l >> 3);
          const int wr = ((wl & 7) << 3) | (l & 7);
          const int hh = (hr + 60) & 63, ww = (wr + 60) & 63;
          const size_t sp = ((size_t)(b << 12)) | (hh << 6) | ww;
          const float c1 = mvec[b * 4608 + 1536 + col];
          const float xv = xres[sp * 768 + col];
          ((bf16*)outv)[sp * 768 + col] =
              (bf16)((xv + c1 * v) * rsqrtf(1.f + c1 * c1));
        } else {  // MODE 3: fp32 final output
          const int grow = row + mOff;
          const int b = grow >> 12;
          const float c2 = mvec[b * 4608 + 3840 + col];
          const float xv = xres[(size_t)grow * 768 + col];
          ((float*)outv)[(size_t)grow * 768 + col] =
              (xv + c2 * v) * rsqrtf(1.f + c2 * c2);
        }
      }
    }
  }
}

// ---------------------------------------------------------------------------
// Windowed attention, one block per (local window, head). 256 thr = 4 waves.
// qkv chunk-local bf16 (chunk windows x 64 tokens x 2304 [q|k|v]).
// ---------------------------------------------------------------------------
__global__ __launch_bounds__(256) void attn_win(
    const bf16* __restrict__ qkv, const float* __restrict__ theta,
    bf16* __restrict__ ao, int winBase) {
  __shared__ __align__(16) bf16 sQ[64 * 64];
  __shared__ __align__(16) bf16 sK[64 * 64];
  __shared__ __align__(16) bf16 sVT[48 * 64];
  __shared__ __align__(16) bf16 sP[64 * 64];
  const int t = threadIdx.x;
  const int winL = blockIdx.x >> 4, head = blockIdx.x & 15;
  const bf16* qrow = qkv + (size_t)winL * 64 * 2304;

  // ---- stage Q, K with rope (24 complex pairs per token) ----
  for (int i = t; i < 3072; i += 256) {
    const int mat = i / 1536;  // 0=q, 1=k
    const int p = i - mat * 1536;
    const int l = p / 24, d = p - (p / 24) * 24;
    const float ih = (float)(l >> 3), iw = (float)(l & 7);
    const float th = ih * theta[head * 24 + d] + iw * theta[384 + head * 24 + d];
    const float sn = __sinf(th), cs = __cosf(th);
    const size_t base = (size_t)l * 2304 + mat * 768 + head * 48 + 2 * d;
    const float qr = (float)qrow[base];
    const float qi = (float)qrow[base + 1];
    bf16* dst = mat ? sK : sQ;
    dst[l * 64 + 2 * d]     = (bf16)(qr * cs - qi * sn);
    dst[l * 64 + 2 * d + 1] = (bf16)(qr * sn + qi * cs);
  }
  // ---- zero-pad cols 48..63 of Q,K ----
  for (int i = t; i < 2048; i += 256) {
    const int mat = i >> 10, r = i & 1023;
    (mat ? sK : sQ)[(r >> 4) * 64 + 48 + (r & 15)] = (bf16)0.f;
  }
  // ---- stage V transposed: sVT[ch][key] ----
  for (int i = t; i < 3072; i += 256) {
    const int l = i / 48, c = i - (i / 48) * 48;
    sVT[c * 64 + l] = qrow[(size_t)l * 2304 + 1536 + head * 48 + c];
  }
  __syncthreads();

  const int wave = t >> 6, lane = t & 63;
  const int quad = lane >> 4, l16 = lane & 15;

  // ---- scores: wave w handles query rows w*16..w*16+15 vs 64 keys ----
  bf16x8 qf0 = *(const bf16x8*)&sQ[(wave * 16 + l16) * 64 + quad * 8];
  bf16x8 qf1 = *(const bf16x8*)&sQ[(wave * 16 + l16) * 64 + 32 + quad * 8];
  f32x4 sc[4];
#pragma unroll
  for (int nt = 0; nt < 4; ++nt) {
    sc[nt] = (f32x4){0.f, 0.f, 0.f, 0.f};
    bf16x8 kf0 = *(const bf16x8*)&sK[(nt * 16 + l16) * 64 + quad * 8];
    bf16x8 kf1 = *(const bf16x8*)&sK[(nt * 16 + l16) * 64 + 32 + quad * 8];
    sc[nt] = __builtin_amdgcn_mfma_f32_16x16x32_bf16(qf0, kf0, sc[nt], 0, 0, 0);
    sc[nt] = __builtin_amdgcn_mfma_f32_16x16x32_bf16(qf1, kf1, sc[nt], 0, 0, 0);
  }

  // ---- softmax per query row (C layout: col=l16 key, row=quad*4+r) ----
  const float scale = 0.14433756729740643f;  // 1/sqrt(48)
#pragma unroll
  for (int r = 0; r < 4; ++r) {
    float pv[4], mx = -3.4e38f;
#pragma unroll
    for (int nt = 0; nt < 4; ++nt) {
      pv[nt] = sc[nt][r] * scale;
      mx = fmaxf(mx, pv[nt]);
    }
#pragma unroll
    for (int o = 1; o < 16; o <<= 1) mx = fmaxf(mx, __shfl_xor(mx, o, 64));
    float sum = 0.f;
#pragma unroll
    for (int nt = 0; nt < 4; ++nt) {
      pv[nt] = __expf(pv[nt] - mx);
      sum += pv[nt];
    }
#pragma unroll
    for (int o = 1; o < 16; o <<= 1) sum += __shfl_xor(sum, o, 64);
    const float inv = 1.f / sum;
    const int row = wave * 16 + quad * 4 + r;
#pragma unroll
    for (int nt = 0; nt < 4; ++nt)
      sP[row * 64 + nt * 16 + l16] = (bf16)(pv[nt] * inv);
  }
  __syncthreads();

  // ---- O = P @ V : (16x64)@(64x48) per wave ----
  bf16x8 pf0 = *(const bf16x8*)&sP[(wave * 16 + l16) * 64 + quad * 8];
  bf16x8 pf1 = *(const bf16x8*)&sP[(wave * 16 + l16) * 64 + 32 + quad * 8];
#pragma unroll
  for (int nt = 0; nt < 3; ++nt) {
    f32x4 oc = (f32x4){0.f, 0.f, 0.f, 0.f};
    bf16x8 vf0 = *(const bf16x8*)&sVT[(nt * 16 + l16) * 64 + quad * 8];
    bf16x8 vf1 = *(const bf16x8*)&sVT[(nt * 16 + l16) * 64 + 32 + quad * 8];
    oc = __builtin_amdgcn_mfma_f32_16x16x32_bf16(pf0, vf0, oc, 0, 0, 0);
    oc = __builtin_amdgcn_mfma_f32_16x16x32_bf16(pf1, vf1, oc, 0, 0, 0);
#pragma unroll
    for (int r = 0; r < 4; ++r) {
      const int row = wave * 16 + quad * 4 + r;
      ao[((size_t)(winBase + winL) * 64 + row) * 768 + head * 48 + nt * 16 +
         l16] = (bf16)oc[r];
    }
  }
}

// ---------------------------------------------------------------------------
extern "C" void kernel_launch(void* const* d_in, const int* in_sizes, int n_in,
                              void* d_out, int out_size, void* d_ws,
                              size_t ws_size, hipStream_t stream) {
  const float* x      = (const float*)d_in[0];
  const float* mod    = (const float*)d_in[1];
  const float* ada_w1 = (const float*)d_in[2];
  const float* ada_b1 = (const float*)d_in[3];
  const float* ada_w2 = (const float*)d_in[4];
  const float* ada_b2 = (const float*)d_in[5];
  const float* theta  = (const float*)d_in[6];
  const float* qkv_w  = (const float*)d_in[7];
  const float* qkv_b  = (const float*)d_in[8];
  const float* proj_w = (const float*)d_in[9];
  const float* proj_b = (const float*)d_in[10];
  const float* mlp_w1 = (const float*)d_in[11];
  const float* mlp_b1 = (const float*)d_in[12];
  const float* mlp_w2 = (const float*)d_in[13];
  const float* mlp_b2 = (const float*)d_in[14];
  float* outF = (float*)d_out;  // 25,165,824 fp32 = 100.66 MB
  // Upper half of d_out (bytes 50.33MB..100.66MB) = 25,165,824 bf16 slots:
  // used as AO (attention out), then as Z (LN2 out). Lifetime-safe: mlp2
  // chunk c writes fp32 rows [c*CHR,(c+1)*CHR); any overlap with UP touches
  // only Z-chunks already consumed by the same chunk's (stream-ordered,
  // earlier) mlp1 launch.
  bf16* UP = (bf16*)d_out + 25165824;

  char* ws = (char*)d_ws;
  size_t o = 0;
  auto alloc = [&](size_t bytes) -> char* {
    char* p = ws + o;
    o += (bytes + 255) & ~(size_t)255;
    return p;
  };
  bf16* wT_qkv  = (bf16*)alloc((size_t)2304 * 768 * 2);
  bf16* wT_proj = (bf16*)alloc((size_t)768 * 768 * 2);
  bf16* wT_m1   = (bf16*)alloc((size_t)3072 * 768 * 2);
  bf16* wT_m2   = (bf16*)alloc((size_t)768 * 3072 * 2);
  float* hada   = (float*)alloc((size_t)8 * 768 * 4);
  float* mvec   = (float*)alloc((size_t)8 * 4608 * 4);
  bf16* Y  = (bf16*)alloc((size_t)32768 * 768 * 2);   // LN1 out, then Y1

  // Chunk size: largest of {32768, 16384, 4096} rows whose SC fits ws.
  int CHR = 4096;
  if (ws_size >= o + (size_t)32768 * 3072 * 2 + (4 << 20)) CHR = 32768;
  else if (ws_size >= o + (size_t)16384 * 3072 * 2 + (4 << 20)) CHR = 16384;
  bf16* SC = (bf16*)alloc((size_t)CHR * 3072 * 2);
  const int NCH = 32768 / CHR;

  transpose_f32<<<dim3(24, 72), 256, 0, stream>>>(qkv_w, wT_qkv, 768, 2304);
  transpose_f32<<<dim3(24, 24), 256, 0, stream>>>(proj_w, wT_proj, 768, 768);
  transpose_f32<<<dim3(24, 96), 256, 0, stream>>>(mlp_w1, wT_m1, 768, 3072);
  transpose_f32<<<dim3(96, 24), 256, 0, stream>>>(mlp_w2, wT_m2, 3072, 768);
  ada1_kernel<<<dim3(8, 24), 256, 0, stream>>>(mod, ada_w1, ada_b1, hada);
  ada2_kernel<<<dim3(8, 72), 256, 0, stream>>>(hada, ada_w2, ada_b2, mvec);

  // LN1 + modulation, gathered into window-token layout. x fp32 -> Y bf16.
  ln_mod_kernel<1><<<32768, 256, 0, stream>>>(x, mvec, Y, 1);

  // qkv GEMM + attention, NCH chunks of CHR rows (CHR/64 windows). AO -> UP.
  for (int c = 0; c < NCH; ++c) {
    gemm_bt<0><<<dim3(CHR / 128, 18), 256, 0, stream>>>(
        Y + (size_t)c * CHR * 768, wT_qkv, qkv_b, SC, 2304, 768, 0, nullptr,
        mvec);
    attn_win<<<(CHR / 64) * 16, 256, 0, stream>>>(SC, theta, UP,
                                                  c * (CHR / 64));
  }

  // proj GEMM; epilogue un-windows + residual (x fp32) -> Y (=Y1, bf16).
  gemm_bt<2><<<dim3(256, 6), 256, 0, stream>>>(UP, wT_proj, proj_b, Y, 768,
                                               768, 0, x, mvec);

  // LN2 + modulation (spatial layout): Y bf16 -> Z (UP).
  ln_mod_kernel<0><<<32768, 256, 0, stream>>>(Y, mvec, UP, 0);

  // MLP, NCH chunks: mlp1 (silu) -> SC, mlp2 + final residual -> d_out fp32.
  for (int c = 0; c < NCH; ++c) {
    gemm_bt<1><<<dim3(CHR / 128, 24), 256, 0, stream>>>(
        UP + (size_t)c * CHR * 768, wT_m1, mlp_b1, SC, 3072, 768, 0, nullptr,
        mvec);
    gemm_bt<3><<<dim3(CHR / 128, 6), 256, 0, stream>>>(
        SC, wT_m2, mlp_b2, outF, 768, 3072, c * CHR, x, mvec);
  }
  (void)in_sizes; (void)n_in; (void)out_size;
}